// Round 8
// baseline (838.156 us; speedup 1.0000x reference)
//
#include <hip/hip_runtime.h>
#include <hip/hip_bf16.h>
#include <stdint.h>

#define DMODEL 1024
#define NEXP 32
#define ESZ 256
#define NTOK 8192
#define NH 4

typedef __hip_bfloat16 bf16;
typedef short bf16x8 __attribute__((ext_vector_type(8)));
typedef float f32x4 __attribute__((ext_vector_type(4)));
typedef float f32x2 __attribute__((ext_vector_type(2)));

__device__ __forceinline__ void pack8(const float4& a, const float4& b, bf16* t) {
    t[0] = __float2bfloat16(a.x); t[1] = __float2bfloat16(a.y);
    t[2] = __float2bfloat16(a.z); t[3] = __float2bfloat16(a.w);
    t[4] = __float2bfloat16(b.x); t[5] = __float2bfloat16(b.y);
    t[6] = __float2bfloat16(b.z); t[7] = __float2bfloat16(b.w);
}

// packed 2xf32 atomic add (gfx90a+: global_atomic_pk_add_f32) — halves atomic op count
__device__ __forceinline__ void atomic_pk2(float* p, float a, float b) {
#if __has_builtin(__builtin_amdgcn_global_atomic_fadd_v2f32)
    f32x2 v = {a, b};
    __builtin_amdgcn_global_atomic_fadd_v2f32(
        (__attribute__((address_space(1))) f32x2*)p, v);
#else
    unsafeAtomicAdd(p, a);
    unsafeAtomicAdd(p + 1, b);
#endif
}

// ---------------- selection: 2 tokens per wave + fused histogram ----------------
__global__ void sel_kernel(const float* __restrict__ x, const float* __restrict__ esel,
                           int* __restrict__ eidx, float* __restrict__ egate,
                           int* __restrict__ counts_q) {
    int lane = threadIdx.x & 63;
    int wid = threadIdx.x >> 6;
    int t0 = blockIdx.x * 8 + wid * 2;          // this wave: tokens t0, t0+1

    const float* xpA = x + (size_t)t0 * DMODEL + lane * 16;
    const float* xpB = xpA + DMODEL;
    float xa[16], xb[16];
    *(float4*)&xa[0]  = *(const float4*)(xpA);
    *(float4*)&xa[4]  = *(const float4*)(xpA + 4);
    *(float4*)&xa[8]  = *(const float4*)(xpA + 8);
    *(float4*)&xa[12] = *(const float4*)(xpA + 12);
    *(float4*)&xb[0]  = *(const float4*)(xpB);
    *(float4*)&xb[4]  = *(const float4*)(xpB + 4);
    *(float4*)&xb[8]  = *(const float4*)(xpB + 8);
    *(float4*)&xb[12] = *(const float4*)(xpB + 12);

    __shared__ float sc[4][2][NEXP];
    __shared__ int s_sel[4][2][NH];
    for (int e = 0; e < NEXP; ++e) {
        const float* sp = esel + (size_t)e * DMODEL + lane * 16;
        float4 p0 = *(const float4*)(sp);
        float4 p1 = *(const float4*)(sp + 4);
        float4 p2 = *(const float4*)(sp + 8);
        float4 p3 = *(const float4*)(sp + 12);
        float sA = xa[0]*p0.x + xa[1]*p0.y + xa[2]*p0.z + xa[3]*p0.w
                 + xa[4]*p1.x + xa[5]*p1.y + xa[6]*p1.z + xa[7]*p1.w
                 + xa[8]*p2.x + xa[9]*p2.y + xa[10]*p2.z + xa[11]*p2.w
                 + xa[12]*p3.x + xa[13]*p3.y + xa[14]*p3.z + xa[15]*p3.w;
        float sB = xb[0]*p0.x + xb[1]*p0.y + xb[2]*p0.z + xb[3]*p0.w
                 + xb[4]*p1.x + xb[5]*p1.y + xb[6]*p1.z + xb[7]*p1.w
                 + xb[8]*p2.x + xb[9]*p2.y + xb[10]*p2.z + xb[11]*p2.w
                 + xb[12]*p3.x + xb[13]*p3.y + xb[14]*p3.z + xb[15]*p3.w;
        #pragma unroll
        for (int o = 32; o > 0; o >>= 1) {
            sA += __shfl_xor(sA, o, 64);
            sB += __shfl_xor(sB, o, 64);
        }
        if (lane == 0) { sc[wid][0][e] = sA; sc[wid][1][e] = sB; }
    }

    if (lane == 0) {
        // strict > scan: lowest index wins ties (matches lax.top_k; sigmoid is monotone)
        #pragma unroll
        for (int tt = 0; tt < 2; ++tt) {
            for (int j = 0; j < NH; ++j) {
                float m = -1e30f; int mi = 0;
                for (int e = 0; e < NEXP; ++e) {
                    float v = sc[wid][tt][e];
                    if (v > m) { m = v; mi = e; }
                }
                sc[wid][tt][mi] = -1e30f;
                float g = 1.f / (1.f + expf(-m));   // sigmoid of logit
                eidx[(t0 + tt) * NH + j] = mi;
                egate[(t0 + tt) * NH + j] = g;
                s_sel[wid][tt][j] = mi;
            }
        }
    }
    __syncthreads();

    // fused histogram: this block's 32 entries, all in quarter q = blockIdx.x>>8
    if (threadIdx.x < NEXP) {
        int cnt = 0;
        #pragma unroll
        for (int w2 = 0; w2 < 4; ++w2)
            #pragma unroll
            for (int tt = 0; tt < 2; ++tt)
                #pragma unroll
                for (int j = 0; j < NH; ++j)
                    cnt += (s_sel[w2][tt][j] == (int)threadIdx.x);
        if (cnt) atomicAdd(&counts_q[threadIdx.x * 4 + (blockIdx.x >> 8)], cnt);
    }
}

// ---------------- deterministic ballot compaction (inline prefix scan) ----------------
__global__ void compact_kernel(const int* __restrict__ eidx, const float* __restrict__ egate,
                               const int* __restrict__ counts_q,
                               int* __restrict__ btok, float* __restrict__ bgate) {
    int e = blockIdx.x;   // 32
    int q = blockIdx.y;   // 4
    int lane = threadIdx.x;  // block = 64 (one wave)
    int idx = 4 * e + q;
    int s = 0;
    for (int i = lane; i < idx; i += 64) s += counts_q[i];
    #pragma unroll
    for (int o = 32; o > 0; o >>= 1) s += __shfl_xor(s, o, 64);
    int base = s;   // same value in all lanes

    const int* p = eidx + q * 8192;
    const float* g = egate + q * 8192;
    int v = p[lane];
    for (int it = 0; it < 128; ++it) {
        int v_next = (it < 127) ? p[(it + 1) * 64 + lane] : 0;   // prefetch
        unsigned long long m = __ballot(v == e);
        if (v == e) {
            int i = it * 64 + lane;
            int pos = base + __popcll(m & ((1ull << lane) - 1ull));
            btok[pos] = (q * 8192 + i) >> 2;      // token index
            bgate[pos] = g[i];
        }
        base += __popcll(m);
        v = v_next;
    }
}

// ---------------- per-expert transpose+convert: f32 in[e][R][C] -> bf16 out[e][C][R] ----------------
__global__ void transpose_conv_kernel(const float* __restrict__ in, bf16* __restrict__ out,
                                      int R, int C) {
    __shared__ bf16 tile[64][72];
    int e = blockIdx.z, tr = blockIdx.y, tc = blockIdx.x;
    const float* src = in + ((size_t)e * R + tr * 64) * C + tc * 64;
    #pragma unroll
    for (int i = 0; i < 2; ++i) {
        int c = threadIdx.x + 256 * i;
        int r = c >> 3, c8 = c & 7;
        float4 p0 = *(const float4*)(src + (size_t)r * C + c8 * 8);
        float4 p1 = *(const float4*)(src + (size_t)r * C + c8 * 8 + 4);
        bf16 t8[8];
        pack8(p0, p1, t8);
        *(uint4*)&tile[r][c8 * 8] = *(uint4*)t8;
    }
    __syncthreads();
    bf16* dst = out + ((size_t)e * C + tc * 64) * R + tr * 64;
    #pragma unroll
    for (int i = 0; i < 2; ++i) {
        int c = threadIdx.x + 256 * i;
        int oc = c >> 3, c8 = c & 7;
        bf16 tmp[8];
        #pragma unroll
        for (int j = 0; j < 8; ++j) tmp[j] = tile[c8 * 8 + j][oc];
        *(uint4*)(dst + (size_t)oc * R + c8 * 8) = *(uint4*)tmp;
    }
}

// ---------------- grouped expert GEMM v8 ----------------
// v3's proven tile-major grid + T14 reg-prefetch; stage B uses OPERAND-SWAPPED MFMA so each
// thread's f32x4 holds 4 consecutive v-columns of ONE token row -> packed 2xf32 atomics
// (global_atomic_pk_add_f32), halving the epilogue's atomic op count (the dominant cost).
__global__ __launch_bounds__(256, 3) void moe_gemm_kernel(
    const float* __restrict__ x, const bf16* __restrict__ keysT, const bf16* __restrict__ valuesT,
    const int* __restrict__ counts_q,
    const int* __restrict__ btok, const float* __restrict__ bgate,
    float* __restrict__ out) {
    int e = blockIdx.y;            // tile-major linear id: de-pins experts from XCDs
    int tile = blockIdx.x;
    int tid = threadIdx.x;
    int lane = tid & 63;
    int w = tid >> 6;

    // inline header: off = prefix over counts_q[0..4e), n = sum of expert e's 4 quarters
    __shared__ int s_hdr[2];
    if (tid == 0) {
        int o = 0;
        for (int i = 0; i < 4 * e; ++i) o += counts_q[i];
        int nn = counts_q[4*e] + counts_q[4*e+1] + counts_q[4*e+2] + counts_q[4*e+3];
        s_hdr[0] = o; s_hdr[1] = nn;
    }
    __syncthreads();
    int off = s_hdr[0], n = s_hdr[1];
    if (tile * 64 >= n) return;    // uniform exit

    // LDS: stage A uses Xg[64][72] @0 (9216 B) + KT[256][72] @9216 (36864 B) = 46080 B
    //      stage B uses H[64][264] @0 (33792 B) + VT[128][72] @33792 (18432 B) = 52224 B
    __shared__ __align__(16) unsigned char smem[52224];
    bf16* Xg = (bf16*)smem;
    bf16* KT = (bf16*)(smem + 9216);
    bf16* H  = (bf16*)smem;
    bf16* VT = (bf16*)(smem + 33792);
    __shared__ int s_tok[64];
    __shared__ float s_gate[64];

    if (tid < 64) {
        int idxr = tile * 64 + tid;
        bool valid = idxr < n;
        int tok = valid ? btok[off + idxr] : 0;
        s_tok[tid] = tok & (NTOK - 1);           // defensive mask
        float g = valid ? bgate[off + idxr] : 0.f;
        s_gate[tid] = (g == g) ? g : 0.f;        // defensive NaN scrub
    }
    __syncthreads();

    int lr = lane & 15;   // fragment row/col index
    int lg = lane >> 4;   // quad
    int c16 = tid & 7;
    int r0 = tid >> 3;    // 0..31

    f32x4 acc[16] = {};   // wave w: H rows [16w,16w+16) x cols [0,256)

    const bf16* kbase = keysT + (size_t)e * ESZ * DMODEL;
    const bf16* vbase = valuesT + (size_t)e * DMODEL * ESZ;
    const float* xrA = x + (size_t)s_tok[r0] * DMODEL;
    const float* xrB = x + (size_t)s_tok[r0 + 32] * DMODEL;

    // -------- prologue: kb=0 into registers --------
    float4 pa0 = *(const float4*)(xrA + c16 * 8);
    float4 pa1 = *(const float4*)(xrA + c16 * 8 + 4);
    float4 pb0 = *(const float4*)(xrB + c16 * 8);
    float4 pb1 = *(const float4*)(xrB + c16 * 8 + 4);
    uint4 kr[8];
    #pragma unroll
    for (int i = 0; i < 8; ++i)
        kr[i] = *(const uint4*)(kbase + (size_t)(r0 + 32 * i) * DMODEL + c16 * 8);
    uint4 vr[4];

    // =================== stage A: H = relu(X @ K_e) * gate ===================
    for (int kb = 0; kb < 16; ++kb) {
        // write current step's registers to LDS
        {
            bf16 t8[8];
            pack8(pa0, pa1, t8);
            *(uint4*)&Xg[r0 * 72 + c16 * 8] = *(uint4*)t8;
            pack8(pb0, pb1, t8);
            *(uint4*)&Xg[(r0 + 32) * 72 + c16 * 8] = *(uint4*)t8;
        }
        #pragma unroll
        for (int i = 0; i < 8; ++i)
            *(uint4*)&KT[(r0 + 32 * i) * 72 + c16 * 8] = kr[i];
        __syncthreads();
        // T14: issue next step's loads now; MFMA below hides their latency
        if (kb < 15) {
            int nk = kb + 1;
            pa0 = *(const float4*)(xrA + nk * 64 + c16 * 8);
            pa1 = *(const float4*)(xrA + nk * 64 + c16 * 8 + 4);
            pb0 = *(const float4*)(xrB + nk * 64 + c16 * 8);
            pb1 = *(const float4*)(xrB + nk * 64 + c16 * 8 + 4);
            #pragma unroll
            for (int i = 0; i < 8; ++i)
                kr[i] = *(const uint4*)(kbase + (size_t)(r0 + 32 * i) * DMODEL + nk * 64 + c16 * 8);
        } else {
            // prefetch stage B's first VT chunk (vc=0, hc=0)
            #pragma unroll
            for (int i = 0; i < 4; ++i)
                vr[i] = *(const uint4*)(vbase + (size_t)(r0 + 32 * i) * ESZ + c16 * 8);
        }
        #pragma unroll
        for (int ks = 0; ks < 2; ++ks) {
            bf16x8 a = *(bf16x8*)&Xg[(w * 16 + lr) * 72 + ks * 32 + lg * 8];
            #pragma unroll
            for (int ct = 0; ct < 16; ++ct) {
                bf16x8 b = *(bf16x8*)&KT[(ct * 16 + lr) * 72 + ks * 32 + lg * 8];
                acc[ct] = __builtin_amdgcn_mfma_f32_16x16x32_bf16(a, b, acc[ct], 0, 0, 0);
            }
        }
        __syncthreads();
    }

    // relu + gate, f32 -> bf16 into H
    int rbase = w * 16 + lg * 4;
    {
        float g0 = s_gate[rbase + 0], g1 = s_gate[rbase + 1];
        float g2 = s_gate[rbase + 2], g3 = s_gate[rbase + 3];
        #pragma unroll
        for (int ct = 0; ct < 16; ++ct) {
            int col = ct * 16 + lr;
            H[(rbase + 0) * 264 + col] = __float2bfloat16(fmaxf(acc[ct][0], 0.f) * g0);
            H[(rbase + 1) * 264 + col] = __float2bfloat16(fmaxf(acc[ct][1], 0.f) * g1);
            H[(rbase + 2) * 264 + col] = __float2bfloat16(fmaxf(acc[ct][2], 0.f) * g2);
            H[(rbase + 3) * 264 + col] = __float2bfloat16(fmaxf(acc[ct][3], 0.f) * g3);
        }
    }
    __syncthreads();

    // =================== stage B (operand-swapped): Y^T fragments -> pk2 atomics ===================
    // mfma(VT_frag, H_frag, acc): acc col = lane&15 -> TOKEN row (w*16+lr),
    //                             acc row = lg*4+j  -> v column (consecutive!).
    int tok_row = w * 16 + lr;
    bool row_ok = (tile * 64 + tok_row) < n;
    float* orow = out + (size_t)s_tok[tok_row] * DMODEL;
    for (int vc = 0; vc < 8; ++vc) {          // 8 v-chunks of 128
        f32x4 yr[8] = {};
        #pragma unroll
        for (int hc = 0; hc < 4; ++hc) {      // K = 256 in 4 steps
            // write prefetched VT chunk [128 v][64 h]
            #pragma unroll
            for (int i = 0; i < 4; ++i)
                *(uint4*)&VT[(r0 + 32 * i) * 72 + c16 * 8] = vr[i];
            __syncthreads();
            // T14: prefetch next (vc,hc) chunk
            int st = vc * 4 + hc;
            if (st < 31) {
                int ns = st + 1, nvc = ns >> 2, nhc = ns & 3;
                #pragma unroll
                for (int i = 0; i < 4; ++i)
                    vr[i] = *(const uint4*)(vbase + (size_t)(nvc * 128 + r0 + 32 * i) * ESZ
                                            + nhc * 64 + c16 * 8);
            }
            #pragma unroll
            for (int ks = 0; ks < 2; ++ks) {
                bf16x8 hfrag = *(bf16x8*)&H[(w * 16 + lr) * 264 + hc * 64 + ks * 32 + lg * 8];
                #pragma unroll
                for (int ct = 0; ct < 8; ++ct) {
                    bf16x8 vfrag = *(bf16x8*)&VT[(ct * 16 + lr) * 72 + ks * 32 + lg * 8];
                    // SWAPPED: A-operand = V fragment, B-operand = H fragment
                    yr[ct] = __builtin_amdgcn_mfma_f32_16x16x32_bf16(vfrag, hfrag, yr[ct], 0, 0, 0);
                }
            }
            __syncthreads();
        }
        // packed scatter-accumulate: 2 pk2 atomics per fragment (halved op count)
        if (row_ok) {
            #pragma unroll
            for (int ct = 0; ct < 8; ++ct) {
                int v0 = vc * 128 + ct * 16 + lg * 4;
                atomic_pk2(orow + v0,     yr[ct][0], yr[ct][1]);
                atomic_pk2(orow + v0 + 2, yr[ct][2], yr[ct][3]);
            }
        }
    }
}

extern "C" void kernel_launch(void* const* d_in, const int* in_sizes, int n_in,
                              void* d_out, int out_size, void* d_ws, size_t ws_size,
                              hipStream_t stream) {
    const float* x      = (const float*)d_in[0];
    const float* keys   = (const float*)d_in[1];
    const float* values = (const float*)d_in[2];
    const float* esel   = (const float*)d_in[3];
    float* out = (float*)d_out;   // [8192][1024] f32 = 32 MiB, accumulated into directly

    // Workspace map — total within 51380224 B (proven-safe bound):
    uint8_t* ws = (uint8_t*)d_ws;
    int*   eidx     = (int*)(ws);                        // [8192][4]   131072 B
    float* egate    = (float*)(ws + 131072);             // [8192][4]   131072 B
    int*   btok     = (int*)(ws + 262144);               // [32768]     131072 B
    float* bgate    = (float*)(ws + 393216);             // [32768]     131072 B
    int*   counts_q = (int*)(ws + 524288);               // [32][4]     512 B
    bf16*  keysT    = (bf16*)(ws + 1048576);             // 16 MiB: [32][256 h][1024 d]
    bf16*  valuesT  = (bf16*)(ws + 17825792);            // 16 MiB: [32][1024 v][256 h]

    hipMemsetAsync(out, 0, (size_t)NTOK * DMODEL * sizeof(float), stream);
    hipMemsetAsync(counts_q, 0, NEXP * 4 * sizeof(int), stream);

    transpose_conv_kernel<<<dim3(16, 4, 32), 256, 0, stream>>>(values, valuesT, ESZ, DMODEL);
    transpose_conv_kernel<<<dim3(4, 16, 32), 256, 0, stream>>>(keys, keysT, DMODEL, ESZ);
    sel_kernel<<<NTOK / 8, 256, 0, stream>>>(x, esel, eidx, egate, counts_q);
    compact_kernel<<<dim3(NEXP, 4), 64, 0, stream>>>(eidx, egate, counts_q, btok, bgate);
    // tile-major grid (linear id = tile + e*128): experts NOT pinned to XCDs
    moe_gemm_kernel<<<dim3(128, NEXP), 256, 0, stream>>>(x, keysT, valuesT, counts_q,
                                                         btok, bgate, out);
}

// Round 9
// 576.722 us; speedup vs baseline: 1.4533x; 1.4533x over previous
//
#include <hip/hip_runtime.h>
#include <hip/hip_bf16.h>
#include <stdint.h>

#define DMODEL 1024
#define NEXP 32
#define ESZ 256
#define NTOK 8192
#define NH 4

typedef __hip_bfloat16 bf16;
typedef short bf16x8 __attribute__((ext_vector_type(8)));
typedef float f32x4 __attribute__((ext_vector_type(4)));

__device__ __forceinline__ void pack8(const float4& a, const float4& b, bf16* t) {
    t[0] = __float2bfloat16(a.x); t[1] = __float2bfloat16(a.y);
    t[2] = __float2bfloat16(a.z); t[3] = __float2bfloat16(a.w);
    t[4] = __float2bfloat16(b.x); t[5] = __float2bfloat16(b.y);
    t[6] = __float2bfloat16(b.z); t[7] = __float2bfloat16(b.w);
}

// ---------------- selection: 2 tokens per wave + fused histogram (proven v6/v7/v8) ----------------
__global__ void sel_kernel(const float* __restrict__ x, const float* __restrict__ esel,
                           int* __restrict__ eidx, float* __restrict__ egate,
                           int* __restrict__ counts_q) {
    int lane = threadIdx.x & 63;
    int wid = threadIdx.x >> 6;
    int t0 = blockIdx.x * 8 + wid * 2;          // this wave: tokens t0, t0+1

    const float* xpA = x + (size_t)t0 * DMODEL + lane * 16;
    const float* xpB = xpA + DMODEL;
    float xa[16], xb[16];
    *(float4*)&xa[0]  = *(const float4*)(xpA);
    *(float4*)&xa[4]  = *(const float4*)(xpA + 4);
    *(float4*)&xa[8]  = *(const float4*)(xpA + 8);
    *(float4*)&xa[12] = *(const float4*)(xpA + 12);
    *(float4*)&xb[0]  = *(const float4*)(xpB);
    *(float4*)&xb[4]  = *(const float4*)(xpB + 4);
    *(float4*)&xb[8]  = *(const float4*)(xpB + 8);
    *(float4*)&xb[12] = *(const float4*)(xpB + 12);

    __shared__ float sc[4][2][NEXP];
    __shared__ int s_sel[4][2][NH];
    for (int e = 0; e < NEXP; ++e) {
        const float* sp = esel + (size_t)e * DMODEL + lane * 16;
        float4 p0 = *(const float4*)(sp);
        float4 p1 = *(const float4*)(sp + 4);
        float4 p2 = *(const float4*)(sp + 8);
        float4 p3 = *(const float4*)(sp + 12);
        float sA = xa[0]*p0.x + xa[1]*p0.y + xa[2]*p0.z + xa[3]*p0.w
                 + xa[4]*p1.x + xa[5]*p1.y + xa[6]*p1.z + xa[7]*p1.w
                 + xa[8]*p2.x + xa[9]*p2.y + xa[10]*p2.z + xa[11]*p2.w
                 + xa[12]*p3.x + xa[13]*p3.y + xa[14]*p3.z + xa[15]*p3.w;
        float sB = xb[0]*p0.x + xb[1]*p0.y + xb[2]*p0.z + xb[3]*p0.w
                 + xb[4]*p1.x + xb[5]*p1.y + xb[6]*p1.z + xb[7]*p1.w
                 + xb[8]*p2.x + xb[9]*p2.y + xb[10]*p2.z + xb[11]*p2.w
                 + xb[12]*p3.x + xb[13]*p3.y + xb[14]*p3.z + xb[15]*p3.w;
        #pragma unroll
        for (int o = 32; o > 0; o >>= 1) {
            sA += __shfl_xor(sA, o, 64);
            sB += __shfl_xor(sB, o, 64);
        }
        if (lane == 0) { sc[wid][0][e] = sA; sc[wid][1][e] = sB; }
    }

    if (lane == 0) {
        // strict > scan: lowest index wins ties (matches lax.top_k; sigmoid is monotone)
        #pragma unroll
        for (int tt = 0; tt < 2; ++tt) {
            for (int j = 0; j < NH; ++j) {
                float m = -1e30f; int mi = 0;
                for (int e = 0; e < NEXP; ++e) {
                    float v = sc[wid][tt][e];
                    if (v > m) { m = v; mi = e; }
                }
                sc[wid][tt][mi] = -1e30f;
                float g = 1.f / (1.f + expf(-m));   // sigmoid of logit
                eidx[(t0 + tt) * NH + j] = mi;
                egate[(t0 + tt) * NH + j] = g;
                s_sel[wid][tt][j] = mi;
            }
        }
    }
    __syncthreads();

    // fused histogram: this block's 32 entries, all in quarter q = blockIdx.x>>8
    if (threadIdx.x < NEXP) {
        int cnt = 0;
        #pragma unroll
        for (int w2 = 0; w2 < 4; ++w2)
            #pragma unroll
            for (int tt = 0; tt < 2; ++tt)
                #pragma unroll
                for (int j = 0; j < NH; ++j)
                    cnt += (s_sel[w2][tt][j] == (int)threadIdx.x);
        if (cnt) atomicAdd(&counts_q[threadIdx.x * 4 + (blockIdx.x >> 8)], cnt);
    }
}

// ---------------- 1-wave shuffle scan: counts_q -> counts, offsets (proven v6) ----------------
__global__ void scan_kernel(const int* __restrict__ counts_q, int* __restrict__ counts,
                            int* __restrict__ offsets) {
    int lane = threadIdx.x;   // block = 64 (one wave)
    int c = 0;
    if (lane < NEXP)
        c = counts_q[lane * 4] + counts_q[lane * 4 + 1]
          + counts_q[lane * 4 + 2] + counts_q[lane * 4 + 3];
    int v = c;
    #pragma unroll
    for (int o = 1; o < 64; o <<= 1) {
        int u = __shfl_up(v, o, 64);
        if (lane >= o) v += u;
    }
    if (lane < NEXP) { counts[lane] = c; offsets[lane] = v - c; }
}

// ---------------- deterministic ballot compaction into buckets (proven v3/v6) ----------------
__global__ void compact_kernel(const int* __restrict__ eidx, const float* __restrict__ egate,
                               const int* __restrict__ offsets, const int* __restrict__ counts_q,
                               int* __restrict__ btok, float* __restrict__ bgate) {
    int e = blockIdx.x;   // 32
    int q = blockIdx.y;   // 4
    int lane = threadIdx.x;  // block = 64 (one wave)
    int base = offsets[e];
    #pragma unroll
    for (int k = 0; k < 4; ++k) if (k < q) base += counts_q[e * 4 + k];
    const int* p = eidx + q * 8192;
    const float* g = egate + q * 8192;
    int v = p[lane];
    for (int it = 0; it < 128; ++it) {
        int v_next = (it < 127) ? p[(it + 1) * 64 + lane] : 0;   // prefetch
        unsigned long long m = __ballot(v == e);
        if (v == e) {
            int i = it * 64 + lane;
            int pos = base + __popcll(m & ((1ull << lane) - 1ull));
            btok[pos] = (q * 8192 + i) >> 2;      // token index
            bgate[pos] = g[i];
        }
        base += __popcll(m);
        v = v_next;
    }
}

// ---------------- per-expert transpose+convert: f32 in[e][R][C] -> bf16 out[e][C][R] ----------------
__global__ void transpose_conv_kernel(const float* __restrict__ in, bf16* __restrict__ out,
                                      int R, int C) {
    __shared__ bf16 tile[64][72];
    int e = blockIdx.z, tr = blockIdx.y, tc = blockIdx.x;
    const float* src = in + ((size_t)e * R + tr * 64) * C + tc * 64;
    #pragma unroll
    for (int i = 0; i < 2; ++i) {
        int c = threadIdx.x + 256 * i;
        int r = c >> 3, c8 = c & 7;
        float4 p0 = *(const float4*)(src + (size_t)r * C + c8 * 8);
        float4 p1 = *(const float4*)(src + (size_t)r * C + c8 * 8 + 4);
        bf16 t8[8];
        pack8(p0, p1, t8);
        *(uint4*)&tile[r][c8 * 8] = *(uint4*)t8;
    }
    __syncthreads();
    bf16* dst = out + ((size_t)e * C + tc * 64) * R + tr * 64;
    #pragma unroll
    for (int i = 0; i < 2; ++i) {
        int c = threadIdx.x + 256 * i;
        int oc = c >> 3, c8 = c & 7;
        bf16 tmp[8];
        #pragma unroll
        for (int j = 0; j < 8; ++j) tmp[j] = tile[c8 * 8 + j][oc];
        *(uint4*)(dst + (size_t)oc * R + c8 * 8) = *(uint4*)tmp;
    }
}

// ---------------- grouped expert GEMM v9 = v3 structure + T14 reg-prefetch ONLY ----------------
// v3's proven: tile-major grid, 52 KB LDS (3 blocks/CU), 4 waves, 2-barrier steps,
// 16-consecutive-lane coalesced atomic epilogue (64B/row per wave instruction).
// Single delta: X/K/V loads for step k+1 issued right after step k's stage-barrier,
// so the MFMA phase (~400-600 cyc) covers the global-load latency (T14).
__global__ __launch_bounds__(256, 3) void moe_gemm_kernel(
    const float* __restrict__ x, const bf16* __restrict__ keysT, const bf16* __restrict__ valuesT,
    const int* __restrict__ counts, const int* __restrict__ offsets,
    const int* __restrict__ btok, const float* __restrict__ bgate,
    float* __restrict__ out) {
    int e = blockIdx.y;
    int n = counts[e];
    int tile = blockIdx.x;
    if (tile * 64 >= n) return;
    int off = offsets[e];
    int tid = threadIdx.x;
    int lane = tid & 63;
    int w = tid >> 6;

    // LDS: stage A uses Xg[64][72] @0 (9216 B) + KT[256][72] @9216 (36864 B) = 46080 B
    //      stage B uses H[64][264] @0 (33792 B) + VT[128][72] @33792 (18432 B) = 52224 B
    __shared__ __align__(16) unsigned char smem[52224];
    bf16* Xg = (bf16*)smem;
    bf16* KT = (bf16*)(smem + 9216);
    bf16* H  = (bf16*)smem;
    bf16* VT = (bf16*)(smem + 33792);
    __shared__ int s_tok[64];
    __shared__ float s_gate[64];

    if (tid < 64) {
        int idxr = tile * 64 + tid;
        bool valid = idxr < n;
        int tok = valid ? btok[off + idxr] : 0;
        s_tok[tid] = tok & (NTOK - 1);           // defensive mask
        float g = valid ? bgate[off + idxr] : 0.f;
        s_gate[tid] = (g == g) ? g : 0.f;        // defensive NaN scrub
    }
    __syncthreads();

    int lr = lane & 15;   // fragment row/col index
    int lg = lane >> 4;   // quad
    int c16 = tid & 7;
    int r0 = tid >> 3;    // 0..31

    f32x4 acc[16] = {};   // wave w: H rows [16w,16w+16) x cols [0,256)

    const bf16* kbase = keysT + (size_t)e * ESZ * DMODEL;
    const bf16* vbase = valuesT + (size_t)e * DMODEL * ESZ;
    const float* xrA = x + (size_t)s_tok[r0] * DMODEL;
    const float* xrB = x + (size_t)s_tok[r0 + 32] * DMODEL;

    // -------- prologue: kb=0 into registers --------
    float4 pa0 = *(const float4*)(xrA + c16 * 8);
    float4 pa1 = *(const float4*)(xrA + c16 * 8 + 4);
    float4 pb0 = *(const float4*)(xrB + c16 * 8);
    float4 pb1 = *(const float4*)(xrB + c16 * 8 + 4);
    uint4 kr[8];
    #pragma unroll
    for (int i = 0; i < 8; ++i)
        kr[i] = *(const uint4*)(kbase + (size_t)(r0 + 32 * i) * DMODEL + c16 * 8);
    uint4 vr[4];

    // =================== stage A: H = relu(X @ K_e) * gate ===================
    for (int kb = 0; kb < 16; ++kb) {
        // write current step's registers to LDS
        {
            bf16 t8[8];
            pack8(pa0, pa1, t8);
            *(uint4*)&Xg[r0 * 72 + c16 * 8] = *(uint4*)t8;
            pack8(pb0, pb1, t8);
            *(uint4*)&Xg[(r0 + 32) * 72 + c16 * 8] = *(uint4*)t8;
        }
        #pragma unroll
        for (int i = 0; i < 8; ++i)
            *(uint4*)&KT[(r0 + 32 * i) * 72 + c16 * 8] = kr[i];
        __syncthreads();
        // T14: issue next step's loads now; MFMA below hides their latency
        if (kb < 15) {
            int nk = kb + 1;
            pa0 = *(const float4*)(xrA + nk * 64 + c16 * 8);
            pa1 = *(const float4*)(xrA + nk * 64 + c16 * 8 + 4);
            pb0 = *(const float4*)(xrB + nk * 64 + c16 * 8);
            pb1 = *(const float4*)(xrB + nk * 64 + c16 * 8 + 4);
            #pragma unroll
            for (int i = 0; i < 8; ++i)
                kr[i] = *(const uint4*)(kbase + (size_t)(r0 + 32 * i) * DMODEL + nk * 64 + c16 * 8);
        } else {
            // prefetch stage B's first VT chunk (vc=0, hc=0)
            #pragma unroll
            for (int i = 0; i < 4; ++i)
                vr[i] = *(const uint4*)(vbase + (size_t)(r0 + 32 * i) * ESZ + c16 * 8);
        }
        #pragma unroll
        for (int ks = 0; ks < 2; ++ks) {
            bf16x8 a = *(bf16x8*)&Xg[(w * 16 + lr) * 72 + ks * 32 + lg * 8];
            #pragma unroll
            for (int ct = 0; ct < 16; ++ct) {
                bf16x8 b = *(bf16x8*)&KT[(ct * 16 + lr) * 72 + ks * 32 + lg * 8];
                acc[ct] = __builtin_amdgcn_mfma_f32_16x16x32_bf16(a, b, acc[ct], 0, 0, 0);
            }
        }
        __syncthreads();
    }

    // relu + gate, f32 -> bf16 into H
    int rbase = w * 16 + lg * 4;
    {
        float g0 = s_gate[rbase + 0], g1 = s_gate[rbase + 1];
        float g2 = s_gate[rbase + 2], g3 = s_gate[rbase + 3];
        #pragma unroll
        for (int ct = 0; ct < 16; ++ct) {
            int col = ct * 16 + lr;
            H[(rbase + 0) * 264 + col] = __float2bfloat16(fmaxf(acc[ct][0], 0.f) * g0);
            H[(rbase + 1) * 264 + col] = __float2bfloat16(fmaxf(acc[ct][1], 0.f) * g1);
            H[(rbase + 2) * 264 + col] = __float2bfloat16(fmaxf(acc[ct][2], 0.f) * g2);
            H[(rbase + 3) * 264 + col] = __float2bfloat16(fmaxf(acc[ct][3], 0.f) * g3);
        }
    }
    __syncthreads();

    // =================== stage B: Y = H @ V_e -> coalesced atomic out (v3 layout) ===================
    for (int vc = 0; vc < 8; ++vc) {          // 8 v-chunks of 128
        f32x4 yr[8] = {};
        #pragma unroll
        for (int hc = 0; hc < 4; ++hc) {      // K = 256 in 4 steps
            // write prefetched VT chunk [128 v][64 h]
            #pragma unroll
            for (int i = 0; i < 4; ++i)
                *(uint4*)&VT[(r0 + 32 * i) * 72 + c16 * 8] = vr[i];
            __syncthreads();
            // T14: prefetch next (vc,hc) chunk
            int st = vc * 4 + hc;
            if (st < 31) {
                int ns = st + 1, nvc = ns >> 2, nhc = ns & 3;
                #pragma unroll
                for (int i = 0; i < 4; ++i)
                    vr[i] = *(const uint4*)(vbase + (size_t)(nvc * 128 + r0 + 32 * i) * ESZ
                                            + nhc * 64 + c16 * 8);
            }
            #pragma unroll
            for (int ks = 0; ks < 2; ++ks) {
                bf16x8 a = *(bf16x8*)&H[(w * 16 + lr) * 264 + hc * 64 + ks * 32 + lg * 8];
                #pragma unroll
                for (int ct = 0; ct < 8; ++ct) {
                    bf16x8 b = *(bf16x8*)&VT[(ct * 16 + lr) * 72 + ks * 32 + lg * 8];
                    yr[ct] = __builtin_amdgcn_mfma_f32_16x16x32_bf16(a, b, yr[ct], 0, 0, 0);
                }
            }
            __syncthreads();
        }
        // scatter-accumulate: 16 consecutive lanes -> 64 contiguous bytes of one row (coalesced)
        #pragma unroll
        for (int ct = 0; ct < 8; ++ct) {
            int v = vc * 128 + ct * 16 + lr;
            #pragma unroll
            for (int r = 0; r < 4; ++r) {
                int row = rbase + r;
                if (tile * 64 + row < n) {
                    unsafeAtomicAdd(&out[(size_t)s_tok[row] * DMODEL + v], yr[ct][r]);
                }
            }
        }
    }
}

extern "C" void kernel_launch(void* const* d_in, const int* in_sizes, int n_in,
                              void* d_out, int out_size, void* d_ws, size_t ws_size,
                              hipStream_t stream) {
    const float* x      = (const float*)d_in[0];
    const float* keys   = (const float*)d_in[1];
    const float* values = (const float*)d_in[2];
    const float* esel   = (const float*)d_in[3];
    float* out = (float*)d_out;   // [8192][1024] f32 = 32 MiB, accumulated into directly

    // Workspace map — total within 51380224 B (proven-safe bound):
    uint8_t* ws = (uint8_t*)d_ws;
    int*   eidx     = (int*)(ws);                        // [8192][4]   131072 B
    float* egate    = (float*)(ws + 131072);             // [8192][4]   131072 B
    int*   btok     = (int*)(ws + 262144);               // [32768]     131072 B
    float* bgate    = (float*)(ws + 393216);             // [32768]     131072 B
    int*   counts   = (int*)(ws + 524288);               // [32]
    int*   offsets  = (int*)(ws + 524416);               // [32]
    int*   counts_q = (int*)(ws + 524544);               // [32][4]     512 B
    bf16*  keysT    = (bf16*)(ws + 1048576);             // 16 MiB: [32][256 h][1024 d]
    bf16*  valuesT  = (bf16*)(ws + 17825792);            // 16 MiB: [32][1024 v][256 h]

    hipMemsetAsync(out, 0, (size_t)NTOK * DMODEL * sizeof(float), stream);
    hipMemsetAsync(counts_q, 0, NEXP * 4 * sizeof(int), stream);

    transpose_conv_kernel<<<dim3(16, 4, 32), 256, 0, stream>>>(values, valuesT, ESZ, DMODEL);
    transpose_conv_kernel<<<dim3(4, 16, 32), 256, 0, stream>>>(keys, keysT, DMODEL, ESZ);
    sel_kernel<<<NTOK / 8, 256, 0, stream>>>(x, esel, eidx, egate, counts_q);
    scan_kernel<<<1, 64, 0, stream>>>(counts_q, counts, offsets);
    compact_kernel<<<dim3(NEXP, 4), 64, 0, stream>>>(eidx, egate, offsets, counts_q, btok, bgate);
    moe_gemm_kernel<<<dim3(128, NEXP), 256, 0, stream>>>(x, keysT, valuesT, counts, offsets,
                                                         btok, bgate, out);
}

// Round 10
// 408.679 us; speedup vs baseline: 2.0509x; 1.4112x over previous
//
#include <hip/hip_runtime.h>
#include <hip/hip_bf16.h>
#include <stdint.h>

#define DMODEL 1024
#define NEXP 32
#define ESZ 256
#define NTOK 8192
#define NH 4

typedef __hip_bfloat16 bf16;
typedef short bf16x8 __attribute__((ext_vector_type(8)));
typedef float f32x4 __attribute__((ext_vector_type(4)));

__device__ __forceinline__ void pack8(const float4& a, const float4& b, bf16* t) {
    t[0] = __float2bfloat16(a.x); t[1] = __float2bfloat16(a.y);
    t[2] = __float2bfloat16(a.z); t[3] = __float2bfloat16(a.w);
    t[4] = __float2bfloat16(b.x); t[5] = __float2bfloat16(b.y);
    t[6] = __float2bfloat16(b.z); t[7] = __float2bfloat16(b.w);
}

// ---------------- prep: BOTH transposes in one launch + counts_q zeroing ----------------
// blocks [0,2048): values f32[32][256][1024] -> bf16 valuesT[32][1024][256]
// blocks [2048,4096): keys f32[32][1024][256] -> bf16 keysT[32][256][1024]
// block 0 additionally zeroes counts_q (sel runs strictly after prep on the stream).
__global__ void prep_kernel(const float* __restrict__ values, bf16* __restrict__ valuesT,
                            const float* __restrict__ keys, bf16* __restrict__ keysT,
                            int* __restrict__ counts_q) {
    int i = blockIdx.x;
    if (i == 0 && threadIdx.x < NEXP * 4) counts_q[threadIdx.x] = 0;

    const float* in; bf16* out; int R, C, e, tr, tc;
    if (i < 2048) {           // values part: per expert 64 blocks (tr 0..3, tc 0..15)
        in = values; out = valuesT; R = ESZ; C = DMODEL;
        e = i >> 6; int r = i & 63; tr = r >> 4; tc = r & 15;
    } else {                  // keys part: per expert 64 blocks (tr 0..15, tc 0..3)
        int j = i - 2048;
        in = keys; out = keysT; R = DMODEL; C = ESZ;
        e = j >> 6; int r = j & 63; tr = r >> 2; tc = r & 3;
    }

    __shared__ bf16 tile[64][72];
    const float* src = in + ((size_t)e * R + tr * 64) * C + tc * 64;
    #pragma unroll
    for (int it = 0; it < 2; ++it) {
        int c = threadIdx.x + 256 * it;
        int r = c >> 3, c8 = c & 7;
        float4 p0 = *(const float4*)(src + (size_t)r * C + c8 * 8);
        float4 p1 = *(const float4*)(src + (size_t)r * C + c8 * 8 + 4);
        bf16 t8[8];
        pack8(p0, p1, t8);
        *(uint4*)&tile[r][c8 * 8] = *(uint4*)t8;
    }
    __syncthreads();
    bf16* dst = out + ((size_t)e * C + tc * 64) * R + tr * 64;
    #pragma unroll
    for (int it = 0; it < 2; ++it) {
        int c = threadIdx.x + 256 * it;
        int oc = c >> 3, c8 = c & 7;
        bf16 tmp[8];
        #pragma unroll
        for (int j = 0; j < 8; ++j) tmp[j] = tile[c8 * 8 + j][oc];
        *(uint4*)(dst + (size_t)oc * R + c8 * 8) = *(uint4*)tmp;
    }
}

// ---------------- selection: 2 tokens/wave + fused histogram + out-slice zeroing ----------------
__global__ void sel_kernel(const float* __restrict__ x, const float* __restrict__ esel,
                           int* __restrict__ eidx, float* __restrict__ egate,
                           int* __restrict__ counts_q, float* __restrict__ out) {
    int lane = threadIdx.x & 63;
    int wid = threadIdx.x >> 6;
    int t0 = blockIdx.x * 8 + wid * 2;          // this wave: tokens t0, t0+1

    // zero this block's 8-token slice of out (replaces the 32 MB memset node)
    {
        float4 z4 = {0.f, 0.f, 0.f, 0.f};
        float* ob = out + (size_t)blockIdx.x * 8 * DMODEL;
        #pragma unroll
        for (int it = 0; it < 8; ++it)
            *(float4*)(ob + it * 1024 + threadIdx.x * 4) = z4;
    }

    const float* xpA = x + (size_t)t0 * DMODEL + lane * 16;
    const float* xpB = xpA + DMODEL;
    float xa[16], xb[16];
    *(float4*)&xa[0]  = *(const float4*)(xpA);
    *(float4*)&xa[4]  = *(const float4*)(xpA + 4);
    *(float4*)&xa[8]  = *(const float4*)(xpA + 8);
    *(float4*)&xa[12] = *(const float4*)(xpA + 12);
    *(float4*)&xb[0]  = *(const float4*)(xpB);
    *(float4*)&xb[4]  = *(const float4*)(xpB + 4);
    *(float4*)&xb[8]  = *(const float4*)(xpB + 8);
    *(float4*)&xb[12] = *(const float4*)(xpB + 12);

    __shared__ float sc[4][2][NEXP];
    __shared__ int s_sel[4][2][NH];
    for (int e = 0; e < NEXP; ++e) {
        const float* sp = esel + (size_t)e * DMODEL + lane * 16;
        float4 p0 = *(const float4*)(sp);
        float4 p1 = *(const float4*)(sp + 4);
        float4 p2 = *(const float4*)(sp + 8);
        float4 p3 = *(const float4*)(sp + 12);
        float sA = xa[0]*p0.x + xa[1]*p0.y + xa[2]*p0.z + xa[3]*p0.w
                 + xa[4]*p1.x + xa[5]*p1.y + xa[6]*p1.z + xa[7]*p1.w
                 + xa[8]*p2.x + xa[9]*p2.y + xa[10]*p2.z + xa[11]*p2.w
                 + xa[12]*p3.x + xa[13]*p3.y + xa[14]*p3.z + xa[15]*p3.w;
        float sB = xb[0]*p0.x + xb[1]*p0.y + xb[2]*p0.z + xb[3]*p0.w
                 + xb[4]*p1.x + xb[5]*p1.y + xb[6]*p1.z + xb[7]*p1.w
                 + xb[8]*p2.x + xb[9]*p2.y + xb[10]*p2.z + xb[11]*p2.w
                 + xb[12]*p3.x + xb[13]*p3.y + xb[14]*p3.z + xb[15]*p3.w;
        #pragma unroll
        for (int o = 32; o > 0; o >>= 1) {
            sA += __shfl_xor(sA, o, 64);
            sB += __shfl_xor(sB, o, 64);
        }
        if (lane == 0) { sc[wid][0][e] = sA; sc[wid][1][e] = sB; }
    }

    if (lane == 0) {
        // strict > scan: lowest index wins ties (matches lax.top_k; sigmoid is monotone)
        #pragma unroll
        for (int tt = 0; tt < 2; ++tt) {
            for (int j = 0; j < NH; ++j) {
                float m = -1e30f; int mi = 0;
                for (int e = 0; e < NEXP; ++e) {
                    float v = sc[wid][tt][e];
                    if (v > m) { m = v; mi = e; }
                }
                sc[wid][tt][mi] = -1e30f;
                float g = 1.f / (1.f + expf(-m));   // sigmoid of logit
                eidx[(t0 + tt) * NH + j] = mi;
                egate[(t0 + tt) * NH + j] = g;
                s_sel[wid][tt][j] = mi;
            }
        }
    }
    __syncthreads();

    // fused histogram: this block's 32 entries, all in quarter q = blockIdx.x>>8
    if (threadIdx.x < NEXP) {
        int cnt = 0;
        #pragma unroll
        for (int w2 = 0; w2 < 4; ++w2)
            #pragma unroll
            for (int tt = 0; tt < 2; ++tt)
                #pragma unroll
                for (int j = 0; j < NH; ++j)
                    cnt += (s_sel[w2][tt][j] == (int)threadIdx.x);
        if (cnt) atomicAdd(&counts_q[threadIdx.x * 4 + (blockIdx.x >> 8)], cnt);
    }
}

// ---------------- compaction with inline prefix scan; block (e,0) publishes counts/offsets ----------------
__global__ void compact_kernel(const int* __restrict__ eidx, const float* __restrict__ egate,
                               const int* __restrict__ counts_q,
                               int* __restrict__ btok, float* __restrict__ bgate,
                               int* __restrict__ counts, int* __restrict__ offsets) {
    int e = blockIdx.x;   // 32
    int q = blockIdx.y;   // 4
    int lane = threadIdx.x;  // block = 64 (one wave)
    int idx = 4 * e + q;
    int s = 0;
    for (int i = lane; i < idx; i += 64) s += counts_q[i];
    #pragma unroll
    for (int o = 32; o > 0; o >>= 1) s += __shfl_xor(s, o, 64);
    int base = s;   // same value in all lanes = prefix over buckets [0, 4e+q)

    if (q == 0 && lane == 0) {   // publish per-expert header for the gemm
        offsets[e] = base;
        counts[e] = counts_q[4*e] + counts_q[4*e+1] + counts_q[4*e+2] + counts_q[4*e+3];
    }

    const int* p = eidx + q * 8192;
    const float* g = egate + q * 8192;
    int v = p[lane];
    for (int it = 0; it < 128; ++it) {
        int v_next = (it < 127) ? p[(it + 1) * 64 + lane] : 0;   // prefetch
        unsigned long long m = __ballot(v == e);
        if (v == e) {
            int i = it * 64 + lane;
            int pos = base + __popcll(m & ((1ull << lane) - 1ull));
            btok[pos] = (q * 8192 + i) >> 2;      // token index
            bgate[pos] = g[i];
        }
        base += __popcll(m);
        v = v_next;
    }
}

// ---------------- grouped expert GEMM: EXACT proven v3 structure ----------------
// Round-0's f32+pack8 staging (proven 191 µs) + round-3's direct-atomic epilogue (proven 193 µs).
// 52 KB LDS -> 3 blocks/CU, 4 waves, 2-barrier steps, tile-major grid, no prefetch grafts.
__global__ __launch_bounds__(256) void moe_gemm_kernel(
    const float* __restrict__ x, const bf16* __restrict__ keysT, const bf16* __restrict__ valuesT,
    const int* __restrict__ counts, const int* __restrict__ offsets,
    const int* __restrict__ btok, const float* __restrict__ bgate,
    float* __restrict__ out) {
    int e = blockIdx.y;
    int n = counts[e];
    int tile = blockIdx.x;
    if (tile * 64 >= n) return;
    int off = offsets[e];
    int tid = threadIdx.x;
    int lane = tid & 63;
    int w = tid >> 6;

    // LDS: stage A uses Xg[64][72] @0 (9216 B) + KT[256][72] @9216 (36864 B) = 46080 B
    //      stage B uses H[64][264] @0 (33792 B) + VT[128][72] @33792 (18432 B) = 52224 B
    __shared__ __align__(16) unsigned char smem[52224];
    bf16* Xg = (bf16*)smem;
    bf16* KT = (bf16*)(smem + 9216);
    bf16* H  = (bf16*)smem;
    bf16* VT = (bf16*)(smem + 33792);
    __shared__ int s_tok[64];
    __shared__ float s_gate[64];

    if (tid < 64) {
        int idxr = tile * 64 + tid;
        bool valid = idxr < n;
        int tok = valid ? btok[off + idxr] : 0;
        s_tok[tid] = tok & (NTOK - 1);           // defensive mask
        float g = valid ? bgate[off + idxr] : 0.f;
        s_gate[tid] = (g == g) ? g : 0.f;        // defensive NaN scrub
    }
    __syncthreads();

    int lr = lane & 15;   // fragment row/col index
    int lg = lane >> 4;   // quad
    int c16 = tid & 7;
    int r0 = tid >> 3;    // 0..31

    f32x4 acc[16] = {};   // wave w: H rows [16w,16w+16) x cols [0,256)

    const bf16* kbase = keysT + (size_t)e * ESZ * DMODEL;
    const float* xrA = x + (size_t)s_tok[r0] * DMODEL;
    const float* xrB = x + (size_t)s_tok[r0 + 32] * DMODEL;

    for (int kb = 0; kb < 16; ++kb) {
        // stage Xg [64][64] with inline f32 -> bf16 conversion
        {
            float4 a0 = *(const float4*)(xrA + kb * 64 + c16 * 8);
            float4 a1 = *(const float4*)(xrA + kb * 64 + c16 * 8 + 4);
            bf16 t8[8];
            pack8(a0, a1, t8);
            *(uint4*)&Xg[r0 * 72 + c16 * 8] = *(uint4*)t8;
            float4 b0 = *(const float4*)(xrB + kb * 64 + c16 * 8);
            float4 b1 = *(const float4*)(xrB + kb * 64 + c16 * 8 + 4);
            pack8(b0, b1, t8);
            *(uint4*)&Xg[(r0 + 32) * 72 + c16 * 8] = *(uint4*)t8;
        }
        // stage KT [256][64] (keysT rows are contiguous in d, already bf16)
        #pragma unroll
        for (int i = 0; i < 8; ++i) {
            int h = r0 + 32 * i;
            *(uint4*)&KT[h * 72 + c16 * 8] =
                *(const uint4*)(kbase + (size_t)h * DMODEL + kb * 64 + c16 * 8);
        }
        __syncthreads();
        #pragma unroll
        for (int ks = 0; ks < 2; ++ks) {
            bf16x8 a = *(bf16x8*)&Xg[(w * 16 + lr) * 72 + ks * 32 + lg * 8];
            #pragma unroll
            for (int ct = 0; ct < 16; ++ct) {
                bf16x8 b = *(bf16x8*)&KT[(ct * 16 + lr) * 72 + ks * 32 + lg * 8];
                acc[ct] = __builtin_amdgcn_mfma_f32_16x16x32_bf16(a, b, acc[ct], 0, 0, 0);
            }
        }
        __syncthreads();
    }

    // relu + gate, f32 -> bf16 into H
    int rbase = w * 16 + lg * 4;
    {
        float g0 = s_gate[rbase + 0], g1 = s_gate[rbase + 1];
        float g2 = s_gate[rbase + 2], g3 = s_gate[rbase + 3];
        #pragma unroll
        for (int ct = 0; ct < 16; ++ct) {
            int col = ct * 16 + lr;
            H[(rbase + 0) * 264 + col] = __float2bfloat16(fmaxf(acc[ct][0], 0.f) * g0);
            H[(rbase + 1) * 264 + col] = __float2bfloat16(fmaxf(acc[ct][1], 0.f) * g1);
            H[(rbase + 2) * 264 + col] = __float2bfloat16(fmaxf(acc[ct][2], 0.f) * g2);
            H[(rbase + 3) * 264 + col] = __float2bfloat16(fmaxf(acc[ct][3], 0.f) * g3);
        }
    }
    __syncthreads();

    // stage B: Y[64][1024] in v-chunks of 128
    const bf16* vbase = valuesT + (size_t)e * DMODEL * ESZ;
    for (int vc = 0; vc < 8; ++vc) {
        f32x4 yr[8] = {};
        #pragma unroll
        for (int hc = 0; hc < 4; ++hc) {
            // stage VT chunk [128 v][64 h] (valuesT rows contiguous in h)
            #pragma unroll
            for (int i = 0; i < 4; ++i) {
                int vr = r0 + 32 * i;
                *(uint4*)&VT[vr * 72 + c16 * 8] =
                    *(const uint4*)(vbase + (size_t)(vc * 128 + vr) * ESZ + hc * 64 + c16 * 8);
            }
            __syncthreads();
            #pragma unroll
            for (int ks = 0; ks < 2; ++ks) {
                bf16x8 a = *(bf16x8*)&H[(w * 16 + lr) * 264 + hc * 64 + ks * 32 + lg * 8];
                #pragma unroll
                for (int ct = 0; ct < 8; ++ct) {
                    bf16x8 b = *(bf16x8*)&VT[(ct * 16 + lr) * 72 + ks * 32 + lg * 8];
                    yr[ct] = __builtin_amdgcn_mfma_f32_16x16x32_bf16(a, b, yr[ct], 0, 0, 0);
                }
            }
            __syncthreads();
        }
        // scatter-accumulate: 16 consecutive lanes -> 64 contiguous bytes of one row (coalesced;
        // scalar f32 atomics are fine-grained memory-side: WRITE == payload, v3-verified)
        #pragma unroll
        for (int ct = 0; ct < 8; ++ct) {
            int v = vc * 128 + ct * 16 + lr;
            #pragma unroll
            for (int r = 0; r < 4; ++r) {
                int row = rbase + r;
                if (tile * 64 + row < n) {
                    unsafeAtomicAdd(&out[(size_t)s_tok[row] * DMODEL + v], yr[ct][r]);
                }
            }
        }
    }
}

extern "C" void kernel_launch(void* const* d_in, const int* in_sizes, int n_in,
                              void* d_out, int out_size, void* d_ws, size_t ws_size,
                              hipStream_t stream) {
    const float* x      = (const float*)d_in[0];
    const float* keys   = (const float*)d_in[1];
    const float* values = (const float*)d_in[2];
    const float* esel   = (const float*)d_in[3];
    float* out = (float*)d_out;   // [8192][1024] f32 = 32 MiB; zeroed inside sel_kernel

    // Workspace map — total within 51380224 B (proven-safe bound):
    uint8_t* ws = (uint8_t*)d_ws;
    int*   eidx     = (int*)(ws);                        // [8192][4]   131072 B
    float* egate    = (float*)(ws + 131072);             // [8192][4]   131072 B
    int*   btok     = (int*)(ws + 262144);               // [32768]     131072 B
    float* bgate    = (float*)(ws + 393216);             // [32768]     131072 B
    int*   counts   = (int*)(ws + 524288);               // [32]
    int*   offsets  = (int*)(ws + 524416);               // [32]
    int*   counts_q = (int*)(ws + 524544);               // [32][4]     512 B
    bf16*  keysT    = (bf16*)(ws + 1048576);             // 16 MiB: [32][256 h][1024 d]
    bf16*  valuesT  = (bf16*)(ws + 17825792);            // 16 MiB: [32][1024 v][256 h]

    // 4-node pipeline (was 9-10): prep -> sel -> compact -> gemm
    prep_kernel<<<4096, 256, 0, stream>>>(values, valuesT, keys, keysT, counts_q);
    sel_kernel<<<NTOK / 8, 256, 0, stream>>>(x, esel, eidx, egate, counts_q, out);
    compact_kernel<<<dim3(NEXP, 4), 64, 0, stream>>>(eidx, egate, counts_q, btok, bgate,
                                                     counts, offsets);
    moe_gemm_kernel<<<dim3(128, NEXP), 256, 0, stream>>>(x, keysT, valuesT, counts, offsets,
                                                         btok, bgate, out);
}